// Round 10
// baseline (16459.311 us; speedup 1.0000x reference)
//
#include <hip/hip_runtime.h>
#include <math.h>

// ---------------------------------------------------------------------------
// MIM RNN round 9: launch-count reduction via epilogue fusion.
// 11 launches/step: sthstm(+gate1) -> stocl(+gate2) -> 3x{ A:[MN+mimn_gate,
// S,X,T,MH], B:[MX+mb_gate1], C:[mbl+mb_gate2(+xgen)] }.
// Split-bf16 (3 merged passes), depth-2 A ping-pong, XOR-swizzle LDS.
// ---------------------------------------------------------------------------

#define S 524288  // 8*64*1024
typedef unsigned short us;
typedef __attribute__((ext_vector_type(8))) short bf16x8;
typedef __attribute__((ext_vector_type(16))) float f32x16;

__device__ __forceinline__ float sigf(float x) { return 1.0f / (1.0f + expf(-x)); }
__device__ __forceinline__ us f2bf(float f) {
  unsigned u = __float_as_uint(f);
  u += 0x7fffu + ((u >> 16) & 1u);
  return (us)(u >> 16);
}
__device__ __forceinline__ float bf2f(us h) {
  return __uint_as_float(((unsigned)h) << 16);
}
#define MFMA __builtin_amdgcn_mfma_f32_32x32x16_bf16

struct Job {
  const float* x0; const us* w0a; const us* w0b;
  const float* x1; const us* w1a; const us* w1b;
  int cin0, cin1, taps, type;  // type 0 plain, 2 fused256
  float* out; int outCo, coBase, coCnt, blockStart;
};
struct Ctx {
  int gmode;  // 1 = mimn, 2 = mb_gate1
  const float* ctw; const float* ocw;
  float* dc; float* dhOut;
  const float* Sb; const float* Tb; const float* Xb; const float* QH;
  float* mPtr; float* cPtr; float* ccPtr;
};
struct Batch { Job j[9]; int n; Ctx ctx; };

// ---------------- weight prepack (unchanged layout) -------------------------
__global__ void pack_k(us* dst, const float* src, int srcRow0, int nRows,
                       int dstRow0, int ciBase, int cinSrc, int taps, int KS) {
  int idx = blockIdx.x * 256 + threadIdx.x;
  int total = taps * KS * 4 * 64;
  if (idx >= total) return;
  int l = idx & 63, cb = (idx >> 6) & 3, rest = idx >> 8;
  int ks = rest % KS, tap = rest / KS;
  int co_d = cb * 32 + (l & 31);
  if (co_d < dstRow0 || co_d >= dstRow0 + nRows) return;
  int srcRow = srcRow0 + (co_d - dstRow0);
  size_t AH = (size_t)taps * KS * 2048;
  size_t base = ((size_t)(tap * KS + ks) * 4 + cb) * 512 + (size_t)l * 8;
#pragma unroll
  for (int j = 0; j < 8; ++j) {
    int ci = ciBase + ks * 16 + (l >> 5) * 8 + j;
    float v = src[((size_t)srcRow * cinSrc + ci) * taps + tap];
    us hi = f2bf(v);
    dst[base + j] = hi;
    dst[AH + base + j] = f2bf(v - bf2f(hi));
  }
}
__global__ void tr1_k(const float* __restrict__ src, float* __restrict__ dst,
                      int Cin, int Cout) {
  int idx = blockIdx.x * 256 + threadIdx.x;
  if (idx >= Cout * Cin) return;
  int ci = idx % Cin, co = idx / Cin;
  dst[(size_t)ci * Cout + co] = src[idx];
}
__global__ void build_net_k(const float* __restrict__ frames0, float* __restrict__ net,
                            int t) {
  int idx = blockIdx.x * 256 + threadIdx.x;
  int b = idx >> 14, ch = (idx >> 10) & 15, p = idx & 1023;
  int y = p >> 5, x = p & 31, py = ch >> 2, px = ch & 3;
  net[idx] = frames0[((size_t)b * 10 + t) * 16384 + (y * 4 + py) * 128 + (x * 4 + px)];
}

// ---------------- staging helpers (device) ----------------------------------
// stage nRows rows (img rows rbase..rbase+nRows-1) of up to-32 ci into SH
// (hi) / SH+loOff (lo) with the XOR-swizzled [row][36col x 64B] layout.
__device__ __forceinline__ void stageB(char* SH, int loOff, const float* X, int cin,
                                       int st, int ciCnt, int b, int rbase,
                                       int nRows, int tid) {
  for (int u = tid; u < nRows * 128; u += 256) {
    int cp = u & 15, xq = (u >> 4) & 7, row = u >> 7;
    if (2 * cp < ciCnt) {
      int gy = rbase + row;
      float4 v0 = {0.f, 0.f, 0.f, 0.f}, v1 = {0.f, 0.f, 0.f, 0.f};
      if ((unsigned)gy < 32u) {
        const float* p0 = X + (((size_t)b * cin + st * 32 + 2 * cp) << 10) + gy * 32 + xq * 4;
        v0 = *(const float4*)p0;
        v1 = *(const float4*)(p0 + 1024);
      }
      const float* e0 = (const float*)&v0;
      const float* e1 = (const float*)&v1;
      int base0 = row * 2368 + ((cp >> 2) << 0) * 0;  // slot folded below
      int slot = cp >> 2, boff = (cp & 3) * 4;
#pragma unroll
      for (int e = 0; e < 4; ++e) {
        int col = xq * 4 + 2 + e;
        int off2 = row * 2368 + col * 64 + ((slot ^ ((col >> 1) & 3)) << 4) + boff;
        us h0 = f2bf(e0[e]), h1 = f2bf(e1[e]);
        us lo0 = f2bf(e0[e] - bf2f(h0)), lo1 = f2bf(e1[e] - bf2f(h1));
        *(unsigned*)(SH + off2) = (unsigned)h0 | ((unsigned)h1 << 16);
        *(unsigned*)(SH + loOff + off2) = (unsigned)lo0 | ((unsigned)lo1 << 16);
      }
      (void)base0;
    }
  }
}
__device__ __forceinline__ void haloZero(char* SH, int loOff, int nRows, int tid) {
  int e = tid;
  if (e < nRows * 32) {
    int hh = e & 1, sl = (e >> 1) & 3;
    int rq = e >> 3;
    int row = rq % nRows, cq2 = rq / nRows;
    int col = cq2 < 2 ? cq2 : 32 + cq2;
    float4 z = {0.f, 0.f, 0.f, 0.f};
    *(float4*)(SH + (hh ? loOff : 0) + row * 2368 + col * 64 + sl * 16) = z;
  }
}

// ---------------- batched conv: plain (R9) + fused256(+gate) ---------------
__global__ __launch_bounds__(256, 2) void convB_k(Batch bt) {
  __shared__ __align__(16) char u[65536];
  int blk = blockIdx.x, ji = 0;
#pragma unroll
  for (int q = 1; q < 9; ++q)
    if (q < bt.n && blk >= bt.j[q].blockStart) ji = q;
  Job J = bt.j[ji];
  int local = blk - J.blockStart;
  int tid = threadIdx.x, l = tid & 63, wv = tid >> 6;
  int lcol = l & 31, lg = l >> 5;

  if (J.type == 0) {
    // ---- plain: 128co x 128px (4 rows), 64 blocks/job ----
    int pxg = local & 7, b = local >> 3, r0 = pxg * 4;
    int wc = wv & 1, wr = wv >> 1;
    const int LO = 8 * 2368;
    f32x16 acc[2][2];
#pragma unroll
    for (int r = 0; r < 2; ++r)
#pragma unroll
      for (int j2 = 0; j2 < 2; ++j2)
#pragma unroll
        for (int q = 0; q < 16; ++q) acc[r][j2][q] = 0.f;
    haloZero(u, LO, 8, tid);
    for (int s = 0; s < 2; ++s) {
      const float* X = s ? J.x1 : J.x0;
      const us* W = s ? J.w1a : J.w0a;
      int cin = s ? J.cin1 : J.cin0;
      if (cin == 0) continue;
      int KS = cin >> 4;
      size_t AH = (size_t)J.taps * KS * 2048;
      int nst = (cin + 31) >> 5;
      for (int st = 0; st < nst; ++st) {
        int ciCnt = cin - st * 32;
        if (ciCnt > 32) ciCnt = 32;
        int kls = ciCnt >> 4, kshift = kls >> 1, NS = J.taps * kls;
        auto aaddr = [&](int uu2) {
          int tap = uu2 >> kshift, kk = uu2 & (kls - 1);
          return W + (((size_t)tap * KS + st * 2 + kk) * 4 + wc * 2) * 512 + (size_t)l * 8;
        };
        bf16x8 pah0, pah1, pal0, pal1, pbh0, pbh1, pbl0, pbl1;
        {
          const us* wp = aaddr(0);
          pah0 = *(const bf16x8*)wp; pah1 = *(const bf16x8*)(wp + 512);
          pal0 = *(const bf16x8*)(wp + AH); pal1 = *(const bf16x8*)(wp + AH + 512);
        }
        if (NS > 1) {
          const us* wp = aaddr(1);
          pbh0 = *(const bf16x8*)wp; pbh1 = *(const bf16x8*)(wp + 512);
          pbl0 = *(const bf16x8*)(wp + AH); pbl1 = *(const bf16x8*)(wp + AH + 512);
        }
        __syncthreads();
        stageB(u, LO, X, cin, st, ciCnt, b, r0 - 2, 8, tid);
        __syncthreads();
        auto slice = [&](int uu2, bf16x8 ah0, bf16x8 ah1, bf16x8 al0, bf16x8 al1) {
          int tap = uu2 >> kshift, kk = uu2 & (kls - 1);
          int dy, dx;
          if (J.taps == 1) { dy = 2; dx = 2; }
          else { dy = tap / 5; dx = tap - dy * 5; }
          int col = lcol + dx, cOff = col * 64, swz = (col >> 1) & 3;
          int phys = (((kk * 2 + lg) ^ swz) << 4);
          const char* p0 = u + (wr * 2 + dy) * 2368 + cOff + phys;
          const char* p1 = u + (wr * 2 + 1 + dy) * 2368 + cOff + phys;
          bf16x8 b0 = *(const bf16x8*)p0, b1 = *(const bf16x8*)p1;
          acc[0][0] = MFMA(ah0, b0, acc[0][0], 0, 0, 0);
          acc[1][0] = MFMA(ah1, b0, acc[1][0], 0, 0, 0);
          acc[0][1] = MFMA(ah0, b1, acc[0][1], 0, 0, 0);
          acc[1][1] = MFMA(ah1, b1, acc[1][1], 0, 0, 0);
          acc[0][0] = MFMA(al0, b0, acc[0][0], 0, 0, 0);
          acc[1][0] = MFMA(al1, b0, acc[1][0], 0, 0, 0);
          acc[0][1] = MFMA(al0, b1, acc[0][1], 0, 0, 0);
          acc[1][1] = MFMA(al1, b1, acc[1][1], 0, 0, 0);
          b0 = *(const bf16x8*)(p0 + LO); b1 = *(const bf16x8*)(p1 + LO);
          acc[0][0] = MFMA(ah0, b0, acc[0][0], 0, 0, 0);
          acc[1][0] = MFMA(ah1, b0, acc[1][0], 0, 0, 0);
          acc[0][1] = MFMA(ah0, b1, acc[0][1], 0, 0, 0);
          acc[1][1] = MFMA(ah1, b1, acc[1][1], 0, 0, 0);
        };
        for (int uu = 0; uu < NS; uu += 2) {
          slice(uu, pah0, pah1, pal0, pal1);
          if (uu + 2 < NS) {
            const us* wp = aaddr(uu + 2);
            pah0 = *(const bf16x8*)wp; pah1 = *(const bf16x8*)(wp + 512);
            pal0 = *(const bf16x8*)(wp + AH); pal1 = *(const bf16x8*)(wp + AH + 512);
          }
          if (uu + 1 < NS) {
            slice(uu + 1, pbh0, pbh1, pbl0, pbl1);
            if (uu + 3 < NS) {
              const us* wp = aaddr(uu + 3);
              pbh0 = *(const bf16x8*)wp; pbh1 = *(const bf16x8*)(wp + 512);
              pbl0 = *(const bf16x8*)(wp + AH); pbl1 = *(const bf16x8*)(wp + AH + 512);
            }
          }
        }
      }
    }
#pragma unroll
    for (int r = 0; r < 2; ++r)
#pragma unroll
      for (int j2 = 0; j2 < 2; ++j2) {
        int prow = r0 + wr * 2 + j2;
        float* op = J.out + (((size_t)b * J.outCo) << 10) + prow * 32 + lcol;
#pragma unroll
        for (int q = 0; q < 16; ++q) {
          int coLoc = wc * 64 + r * 32 + 4 * lg + (q & 3) + 8 * (q >> 2);
          if (coLoc < J.coCnt) op[(size_t)(J.coBase + coLoc) << 10] = acc[r][j2][q];
        }
      }
  } else {
    // ---- fused256: 256co x 64px (2 rows), 128 blocks; gate in epilogue ----
    int pxg = local & 15, b = local >> 4, r0 = pxg * 2;
    int half = wv >> 1, cq = wv & 1;
    const int LO = 6 * 2368;
    f32x16 acc[2][2];  // [ct][row]
#pragma unroll
    for (int r = 0; r < 2; ++r)
#pragma unroll
      for (int j2 = 0; j2 < 2; ++j2)
#pragma unroll
        for (int q = 0; q < 16; ++q) acc[r][j2][q] = 0.f;
    __syncthreads();  // ensure any previous exch use done (paranoia)
    haloZero(u, LO, 6, tid);
    for (int s = 0; s < 2; ++s) {
      const float* X = s ? J.x1 : J.x0;
      const us* W = s ? (half ? J.w1b : J.w1a) : (half ? J.w0b : J.w0a);
      int cin = s ? J.cin1 : J.cin0;
      if (cin == 0) continue;
      int KS = cin >> 4;
      size_t AH = (size_t)J.taps * KS * 2048;
      int nst = (cin + 31) >> 5;
      for (int st = 0; st < nst; ++st) {
        int ciCnt = cin - st * 32;
        if (ciCnt > 32) ciCnt = 32;
        int kls = ciCnt >> 4, kshift = kls >> 1, NS = J.taps * kls;
        auto aaddr = [&](int uu2) {
          int tap = uu2 >> kshift, kk = uu2 & (kls - 1);
          return W + (((size_t)tap * KS + st * 2 + kk) * 4 + cq * 2) * 512 + (size_t)l * 8;
        };
        bf16x8 pah0, pah1, pal0, pal1, pbh0, pbh1, pbl0, pbl1;
        {
          const us* wp = aaddr(0);
          pah0 = *(const bf16x8*)wp; pah1 = *(const bf16x8*)(wp + 512);
          pal0 = *(const bf16x8*)(wp + AH); pal1 = *(const bf16x8*)(wp + AH + 512);
        }
        if (NS > 1) {
          const us* wp = aaddr(1);
          pbh0 = *(const bf16x8*)wp; pbh1 = *(const bf16x8*)(wp + 512);
          pbl0 = *(const bf16x8*)(wp + AH); pbl1 = *(const bf16x8*)(wp + AH + 512);
        }
        __syncthreads();
        stageB(u, LO, X, cin, st, ciCnt, b, r0 - 2, 6, tid);
        __syncthreads();
        auto slice = [&](int uu2, bf16x8 ah0, bf16x8 ah1, bf16x8 al0, bf16x8 al1) {
          int tap = uu2 >> kshift, kk = uu2 & (kls - 1);
          int dy = tap / 5, dx = tap - dy * 5;
          int col = lcol + dx, cOff = col * 64, swz = (col >> 1) & 3;
          int phys = (((kk * 2 + lg) ^ swz) << 4);
          const char* p0 = u + (0 + dy) * 2368 + cOff + phys;
          const char* p1 = u + (1 + dy) * 2368 + cOff + phys;
          bf16x8 b0 = *(const bf16x8*)p0, b1 = *(const bf16x8*)p1;
          acc[0][0] = MFMA(ah0, b0, acc[0][0], 0, 0, 0);
          acc[1][0] = MFMA(ah1, b0, acc[1][0], 0, 0, 0);
          acc[0][1] = MFMA(ah0, b1, acc[0][1], 0, 0, 0);
          acc[1][1] = MFMA(ah1, b1, acc[1][1], 0, 0, 0);
          acc[0][0] = MFMA(al0, b0, acc[0][0], 0, 0, 0);
          acc[1][0] = MFMA(al1, b0, acc[1][0], 0, 0, 0);
          acc[0][1] = MFMA(al0, b1, acc[0][1], 0, 0, 0);
          acc[1][1] = MFMA(al1, b1, acc[1][1], 0, 0, 0);
          b0 = *(const bf16x8*)(p0 + LO); b1 = *(const bf16x8*)(p1 + LO);
          acc[0][0] = MFMA(ah0, b0, acc[0][0], 0, 0, 0);
          acc[1][0] = MFMA(ah1, b0, acc[1][0], 0, 0, 0);
          acc[0][1] = MFMA(ah0, b1, acc[0][1], 0, 0, 0);
          acc[1][1] = MFMA(ah1, b1, acc[1][1], 0, 0, 0);
        };
        for (int uu = 0; uu < NS; uu += 2) {
          slice(uu, pah0, pah1, pal0, pal1);
          if (uu + 2 < NS) {
            const us* wp = aaddr(uu + 2);
            pah0 = *(const bf16x8*)wp; pah1 = *(const bf16x8*)(wp + 512);
            pal0 = *(const bf16x8*)(wp + AH); pal1 = *(const bf16x8*)(wp + AH + 512);
          }
          if (uu + 1 < NS) {
            slice(uu + 1, pbh0, pbh1, pbl0, pbl1);
            if (uu + 3 < NS) {
              const us* wp = aaddr(uu + 3);
              pbh0 = *(const bf16x8*)wp; pbh1 = *(const bf16x8*)(wp + 512);
              pbl0 = *(const bf16x8*)(wp + AH); pbl1 = *(const bf16x8*)(wp + AH + 512);
            }
          }
        }
      }
    }
    // epilogue: LDS exchange + gate
    __syncthreads();
    float* ex = (float*)u;
#pragma unroll
    for (int ct = 0; ct < 2; ++ct)
#pragma unroll
      for (int row = 0; row < 2; ++row)
#pragma unroll
        for (int q = 0; q < 16; ++q) {
          int co = wv * 64 + ct * 32 + 4 * lg + (q & 3) + 8 * (q >> 2);
          ex[co * 64 + row * 32 + lcol] = acc[ct][row][q];
        }
    __syncthreads();
    int pxl = tid & 63, cq3 = tid >> 6;
    size_t pix = (size_t)pxg * 64 + pxl;
    if (bt.ctx.gmode == 1) {
#pragma unroll
      for (int k = 0; k < 16; ++k) {
        int ch = cq3 * 16 + k;
        int rr = ch * 1024 + (int)pix;
        size_t idx = (size_t)b * 65536 + rr;
        float i_ = ex[ch * 64 + pxl], g_ = ex[(64 + ch) * 64 + pxl];
        float f_ = ex[(128 + ch) * 64 + pxl], o_ = ex[(192 + ch) * 64 + pxl];
        float c0 = bt.ctx.dc[idx];
        float cn = sigf(f_ + c0 * bt.ctx.ctw[65536 + rr] + 1.f) * c0 +
                   sigf(i_ + c0 * bt.ctx.ctw[rr]) * tanhf(g_);
        float hn = sigf(o_ + cn * bt.ctx.ocw[rr]) * tanhf(cn);
        bt.ctx.dc[idx] = cn;
        bt.ctx.dhOut[idx] = hn;
      }
    } else {
#pragma unroll
      for (int k = 0; k < 16; ++k) {
        int ch = cq3 * 16 + k;
        int rr = ch * 1024 + (int)pix;
        size_t idx = (size_t)b * 65536 + rr;
        float qx_i = ex[ch * 64 + pxl], qx_g = ex[(64 + ch) * 64 + pxl];
        float qx_f = ex[(128 + ch) * 64 + pxl], qx_o = ex[(192 + ch) * 64 + pxl];
        const float* sb = bt.ctx.Sb + (size_t)b * 262144 + rr;
        const float* tb = bt.ctx.Tb + (size_t)b * 196608 + rr;
        const float* xb = bt.ctx.Xb + (size_t)b * 262144 + rr;
        const float* qh = bt.ctx.QH + (size_t)b * 262144 + rr;
        float i_s = sb[0], g_s = sb[65536], f_s = sb[131072];
        float i_t = tb[0], g_t = tb[65536];
        float i_x = xb[0], g_x = xb[65536], f_x = xb[131072];
        float m0 = bt.ctx.mPtr[idx];
        float nm = sigf(f_x + f_s + 1.f) * m0 + sigf(i_x + i_s) * tanhf(g_x + g_s);
        float q_i = qh[0] + qx_i, q_g = qh[65536] + qx_g;
        float q_f = qh[131072] + qx_f, q_o = qh[196608] + qx_o;
        float cc0 = bt.ctx.ccPtr[idx];
        float mims = sigf(q_f + cc0 * bt.ctx.ctw[65536 + rr] + 1.f) * cc0 +
                     sigf(q_i + cc0 * bt.ctx.ctw[rr]) * tanhf(q_g);
        float h2 = sigf(q_o + mims * bt.ctx.ocw[rr]) * tanhf(mims);
        float nc = h2 + sigf(i_x + i_t) * tanhf(g_x + g_t);
        bt.ctx.mPtr[idx] = nm;
        bt.ctx.cPtr[idx] = nc;
        bt.ctx.ccPtr[idx] = mims;
      }
    }
  }
}

// ---------------- sthstm: STH+STM convs + st_gate1, 2 passes ----------------
__global__ __launch_bounds__(256, 2) void sthstm_k(
    const float* stIn, const float* hs0, const float* membIn,
    const us* wH0n, const us* wH1n, const us* wH0h, const us* wH1h,
    const us* wM0n, const us* wM1n, const us* wM0m, const us* wM1m,
    float* cs0, float* membOut, float* oSt) {
  __shared__ __align__(16) char u[65536];
  int blk = blockIdx.x;
  int pxg = blk & 15, b = blk >> 4, r0 = pxg * 2;
  int tid = threadIdx.x, l = tid & 63, wv = tid >> 6;
  int lcol = l & 31, lg = l >> 5;
  int half = wv >> 1, cq = wv & 1;
  const int LO = 6 * 2368;
  for (int p = 0; p < 2; ++p) {
    f32x16 acc[2][2];
#pragma unroll
    for (int r = 0; r < 2; ++r)
#pragma unroll
      for (int j2 = 0; j2 < 2; ++j2)
#pragma unroll
        for (int q = 0; q < 16; ++q) acc[r][j2][q] = 0.f;
    __syncthreads();
    haloZero(u, LO, 6, tid);
    for (int s = 0; s < 2; ++s) {
      const float* X = s ? (p ? membIn : hs0) : stIn;
      const us* W = s ? (p ? (half ? wM1m : wM0m) : (half ? wH1h : wH0h))
                      : (p ? (half ? wM1n : wM0n) : (half ? wH1n : wH0n));
      int cin = s ? 64 : 16;
      int KS = cin >> 4;
      size_t AH = (size_t)25 * KS * 2048;
      int nst = (cin + 31) >> 5;
      for (int st = 0; st < nst; ++st) {
        int ciCnt = cin - st * 32;
        if (ciCnt > 32) ciCnt = 32;
        int kls = ciCnt >> 4, kshift = kls >> 1, NS = 25 * kls;
        auto aaddr = [&](int uu2) {
          int tap = uu2 >> kshift, kk = uu2 & (kls - 1);
          return W + (((size_t)tap * KS + st * 2 + kk) * 4 + cq * 2) * 512 + (size_t)l * 8;
        };
        bf16x8 pah0, pah1, pal0, pal1, pbh0, pbh1, pbl0, pbl1;
        {
          const us* wp = aaddr(0);
          pah0 = *(const bf16x8*)wp; pah1 = *(const bf16x8*)(wp + 512);
          pal0 = *(const bf16x8*)(wp + AH); pal1 = *(const bf16x8*)(wp + AH + 512);
        }
        if (NS > 1) {
          const us* wp = aaddr(1);
          pbh0 = *(const bf16x8*)wp; pbh1 = *(const bf16x8*)(wp + 512);
          pbl0 = *(const bf16x8*)(wp + AH); pbl1 = *(const bf16x8*)(wp + AH + 512);
        }
        __syncthreads();
        stageB(u, LO, X, cin, st, ciCnt, b, r0 - 2, 6, tid);
        __syncthreads();
        auto slice = [&](int uu2, bf16x8 ah0, bf16x8 ah1, bf16x8 al0, bf16x8 al1) {
          int tap = uu2 >> kshift, kk = uu2 & (kls - 1);
          int dy = tap / 5, dx = tap - dy * 5;
          int col = lcol + dx, cOff = col * 64, swz = (col >> 1) & 3;
          int phys = (((kk * 2 + lg) ^ swz) << 4);
          const char* p0 = u + (0 + dy) * 2368 + cOff + phys;
          const char* p1 = u + (1 + dy) * 2368 + cOff + phys;
          bf16x8 b0 = *(const bf16x8*)p0, b1 = *(const bf16x8*)p1;
          acc[0][0] = MFMA(ah0, b0, acc[0][0], 0, 0, 0);
          acc[1][0] = MFMA(ah1, b0, acc[1][0], 0, 0, 0);
          acc[0][1] = MFMA(ah0, b1, acc[0][1], 0, 0, 0);
          acc[1][1] = MFMA(ah1, b1, acc[1][1], 0, 0, 0);
          acc[0][0] = MFMA(al0, b0, acc[0][0], 0, 0, 0);
          acc[1][0] = MFMA(al1, b0, acc[1][0], 0, 0, 0);
          acc[0][1] = MFMA(al0, b1, acc[0][1], 0, 0, 0);
          acc[1][1] = MFMA(al1, b1, acc[1][1], 0, 0, 0);
          b0 = *(const bf16x8*)(p0 + LO); b1 = *(const bf16x8*)(p1 + LO);
          acc[0][0] = MFMA(ah0, b0, acc[0][0], 0, 0, 0);
          acc[1][0] = MFMA(ah1, b0, acc[1][0], 0, 0, 0);
          acc[0][1] = MFMA(ah0, b1, acc[0][1], 0, 0, 0);
          acc[1][1] = MFMA(ah1, b1, acc[1][1], 0, 0, 0);
        };
        for (int uu = 0; uu < NS; uu += 2) {
          slice(uu, pah0, pah1, pal0, pal1);
          if (uu + 2 < NS) {
            const us* wp = aaddr(uu + 2);
            pah0 = *(const bf16x8*)wp; pah1 = *(const bf16x8*)(wp + 512);
            pal0 = *(const bf16x8*)(wp + AH); pal1 = *(const bf16x8*)(wp + AH + 512);
          }
          if (uu + 1 < NS) {
            slice(uu + 1, pbh0, pbh1, pbl0, pbl1);
            if (uu + 3 < NS) {
              const us* wp = aaddr(uu + 3);
              pbh0 = *(const bf16x8*)wp; pbh1 = *(const bf16x8*)(wp + 512);
              pbl0 = *(const bf16x8*)(wp + AH); pbl1 = *(const bf16x8*)(wp + AH + 512);
            }
          }
        }
      }
    }
    __syncthreads();
    float* ex = (float*)u;
#pragma unroll
    for (int ct = 0; ct < 2; ++ct)
#pragma unroll
      for (int row = 0; row < 2; ++row)
#pragma unroll
        for (int q = 0; q < 16; ++q) {
          int co = wv * 64 + ct * 32 + 4 * lg + (q & 3) + 8 * (q >> 2);
          ex[co * 64 + row * 32 + lcol] = acc[ct][row][q];
        }
    __syncthreads();
    int pxl = tid & 63, cq3 = tid >> 6;
    int pix = pxg * 64 + pxl;
#pragma unroll
    for (int k = 0; k < 16; ++k) {
      int ch = cq3 * 16 + k;
      int rr = ch * 1024 + pix;
      size_t idx = (size_t)b * 65536 + rr;
      float i_ = ex[ch * 64 + pxl], f_ = ex[(64 + ch) * 64 + pxl];
      float g_ = ex[(128 + ch) * 64 + pxl];
      if (p == 0) {
        float o_ = ex[(192 + ch) * 64 + pxl];
        float cn = sigf(f_ + 1.f) * cs0[idx] + sigf(i_) * tanhf(g_);
        cs0[idx] = cn;
        oSt[idx] = o_;
      } else {
        float mn = sigf(f_ + 1.f) * membIn[idx] + sigf(i_) * tanhf(g_);
        membOut[idx] = mn;
      }
    }
  }
}

// ---------------- stocl: STO(5x5)+CL(1x1) convs + st_gate2 ------------------
__global__ __launch_bounds__(256, 2) void stocl_k(
    const float* cs0, const float* membO, const us* wSa, const us* wSb,
    const us* wCa, const us* wCb, const float* oSt, float* hs0,
    float* diffb) {
  __shared__ __align__(16) char u[37888];
  int blk = blockIdx.x;
  int pxg = blk & 7, b = blk >> 3, r0 = pxg * 4;
  int tid = threadIdx.x, l = tid & 63, wv = tid >> 6;  // wv = row
  int lcol = l & 31, lg = l >> 5;
  const int LO = 8 * 2368;
  f32x16 aS[2], aC[2];
#pragma unroll
  for (int ct = 0; ct < 2; ++ct)
#pragma unroll
    for (int q = 0; q < 16; ++q) { aS[ct][q] = 0.f; aC[ct][q] = 0.f; }
  haloZero(u, LO, 8, tid);
  for (int s = 0; s < 2; ++s) {
    const float* X = s ? membO : cs0;
    const us* Ws = s ? wSb : wSa;
    const us* Wc = s ? wCb : wCa;
    const int KS = 4;  // packs made with cinSrc=128
    size_t AHs = (size_t)25 * KS * 2048, AHc = (size_t)1 * KS * 2048;
    for (int st = 0; st < 2; ++st) {
      __syncthreads();
      stageB(u, LO, X, 64, st, 32, b, r0 - 2, 8, tid);
      __syncthreads();
      auto slice6 = [&](f32x16* A, int dy, int dx, const us* wp2, size_t AH2) {
        int col = lcol + dx, cOff = col * 64, swz = (col >> 1) & 3;
        bf16x8 ah0 = *(const bf16x8*)wp2;
        bf16x8 ah1 = *(const bf16x8*)(wp2 + 512);
        bf16x8 al0 = *(const bf16x8*)(wp2 + AH2);
        bf16x8 al1 = *(const bf16x8*)(wp2 + AH2 + 512);
        // kk folded in caller via phys
        (void)swz; (void)cOff;
        return;  // unused path (kept simple below)
      };
      (void)slice6;
      for (int kk = 0; kk < 2; ++kk) {
        int phsel = kk * 2 + lg;
        // STO: 25 taps
        for (int tap = 0; tap < 25; ++tap) {
          int dy = tap / 5, dx = tap - dy * 5;
          const us* wp = Ws + (((size_t)tap * KS + st * 2 + kk) * 4) * 512 + (size_t)l * 8;
          bf16x8 ah0 = *(const bf16x8*)wp, ah1 = *(const bf16x8*)(wp + 512);
          bf16x8 al0 = *(const bf16x8*)(wp + AHs), al1 = *(const bf16x8*)(wp + AHs + 512);
          int col = lcol + dx, cOff = col * 64, swz = (col >> 1) & 3;
          const char* p0 = u + (wv + dy) * 2368 + cOff + ((phsel ^ swz) << 4);
          bf16x8 b0 = *(const bf16x8*)p0;
          aS[0] = MFMA(ah0, b0, aS[0], 0, 0, 0);
          aS[1] = MFMA(ah1, b0, aS[1], 0, 0, 0);
          aS[0] = MFMA(al0, b0, aS[0], 0, 0, 0);
          aS[1] = MFMA(al1, b0, aS[1], 0, 0, 0);
          b0 = *(const bf16x8*)(p0 + LO);
          aS[0] = MFMA(ah0, b0, aS[0], 0, 0, 0);
          aS[1] = MFMA(ah1, b0, aS[1], 0, 0, 0);
        }
        // CL: center tap
        {
          const us* wp = Wc + (((size_t)0 * KS + st * 2 + kk) * 4) * 512 + (size_t)l * 8;
          bf16x8 ah0 = *(const bf16x8*)wp, ah1 = *(const bf16x8*)(wp + 512);
          bf16x8 al0 = *(const bf16x8*)(wp + AHc), al1 = *(const bf16x8*)(wp + AHc + 512);
          int col = lcol + 2, cOff = col * 64, swz = (col >> 1) & 3;
          const char* p0 = u + (wv + 2) * 2368 + cOff + ((phsel ^ swz) << 4);
          bf16x8 b0 = *(const bf16x8*)p0;
          aC[0] = MFMA(ah0, b0, aC[0], 0, 0, 0);
          aC[1] = MFMA(ah1, b0, aC[1], 0, 0, 0);
          aC[0] = MFMA(al0, b0, aC[0], 0, 0, 0);
          aC[1] = MFMA(al1, b0, aC[1], 0, 0, 0);
          b0 = *(const bf16x8*)(p0 + LO);
          aC[0] = MFMA(ah0, b0, aC[0], 0, 0, 0);
          aC[1] = MFMA(ah1, b0, aC[1], 0, 0, 0);
        }
      }
    }
  }
#pragma unroll
  for (int ct = 0; ct < 2; ++ct)
#pragma unroll
    for (int q = 0; q < 16; ++q) {
      int co = ct * 32 + 4 * lg + (q & 3) + 8 * (q >> 2);
      size_t idx = (size_t)b * 65536 + (size_t)co * 1024 + (r0 + wv) * 32 + lcol;
      float hn = sigf(oSt[idx] + aS[ct][q]) * tanhf(aC[ct][q]);
      float old = hs0[idx];
      hs0[idx] = hn;
      diffb[idx] = hn - old;
    }
}

// ---------------- mbl: mb_last conv1 + mb_gate2 (+xgen/out/netb) -----------
__global__ __launch_bounds__(256, 2) void mbl_k(
    const float* csI, const float* membO, const us* wMa, const us* wMb,
    const float* Sb, const float* Tb, const float* Xb, float* hsI, int xg,
    const float* wwl, float* xgen, float* outp, float* netb,
    const float* frames0, int t) {
  __shared__ __align__(16) char u[19200 + 32768];
  int blk = blockIdx.x;
  int pxg = blk & 7, b = blk >> 3, r0 = pxg * 4;
  int tid = threadIdx.x, l = tid & 63, wv = tid >> 6;  // row
  int lcol = l & 31, lg = l >> 5;
  const int LO = 4 * 2368 * 0 + 9472;  // hi rows 4*2368=9472; lo at +9472
  f32x16 a[2];
#pragma unroll
  for (int ct = 0; ct < 2; ++ct)
#pragma unroll
    for (int q = 0; q < 16; ++q) a[ct][q] = 0.f;
  for (int s = 0; s < 2; ++s) {
    const float* X = s ? membO : csI;
    const us* W = s ? wMb : wMa;
    const int KS = 4;
    size_t AH = (size_t)1 * KS * 2048;
    for (int st = 0; st < 2; ++st) {
      __syncthreads();
      stageB(u, LO, X, 64, st, 32, b, r0, 4, tid);  // rows r0..r0+3, no halo
      __syncthreads();
      for (int kk = 0; kk < 2; ++kk) {
        const us* wp = W + (((size_t)0 * KS + st * 2 + kk) * 4) * 512 + (size_t)l * 8;
        bf16x8 ah0 = *(const bf16x8*)wp, ah1 = *(const bf16x8*)(wp + 512);
        bf16x8 al0 = *(const bf16x8*)(wp + AH), al1 = *(const bf16x8*)(wp + AH + 512);
        int col = lcol + 2, cOff = col * 64, swz = (col >> 1) & 3;
        const char* p0 = u + wv * 2368 + cOff + (((kk * 2 + lg) ^ swz) << 4);
        bf16x8 b0 = *(const bf16x8*)p0;
        a[0] = MFMA(ah0, b0, a[0], 0, 0, 0);
        a[1] = MFMA(ah1, b0, a[1], 0, 0, 0);
        a[0] = MFMA(al0, b0, a[0], 0, 0, 0);
        a[1] = MFMA(al1, b0, a[1], 0, 0, 0);
        b0 = *(const bf16x8*)(p0 + LO);
        a[0] = MFMA(ah0, b0, a[0], 0, 0, 0);
        a[1] = MFMA(ah1, b0, a[1], 0, 0, 0);
      }
    }
  }
  float* xb = (float*)(u + 19200);
#pragma unroll
  for (int ct = 0; ct < 2; ++ct)
#pragma unroll
    for (int q = 0; q < 16; ++q) {
      int co = ct * 32 + 4 * lg + (q & 3) + 8 * (q >> 2);
      int rr = co * 1024 + (r0 + wv) * 32 + lcol;
      size_t idx = (size_t)b * 65536 + rr;
      float osum = Xb[(size_t)b * 262144 + 196608 + rr] +
                   Tb[(size_t)b * 196608 + 131072 + rr] +
                   Sb[(size_t)b * 262144 + 196608 + rr];
      float hn = sigf(osum) * tanhf(a[ct][q]);
      hsI[idx] = hn;
      if (xg) xb[(wv * 64 + co) * 32 + lcol] = hn;
    }
  if (xg) {
    __syncthreads();
    int row = tid >> 6, x = tid & 31, lg2 = (tid >> 5) & 1;
    int y = r0 + row;
#pragma unroll
    for (int c16 = 0; c16 < 8; ++c16) {
      int co = lg2 * 8 + c16;
      float acc2 = 0.f;
      for (int ci = 0; ci < 64; ++ci)
        acc2 = fmaf(wwl[ci * 16 + co], xb[(row * 64 + ci) * 32 + x], acc2);
      int pix = y * 32 + x;
      xgen[(size_t)b * 16384 + (size_t)co * 1024 + pix] = acc2;
      int py = co >> 2, pxs = co & 3;
      if (t >= 9)
        outp[((size_t)b * 10 + (t - 9)) * 16384 + (y * 4 + py) * 128 + x * 4 + pxs] = acc2;
      if (t + 1 < 10)
        netb[(size_t)b * 16384 + (size_t)co * 1024 + pix] =
            frames0[((size_t)b * 10 + (t + 1)) * 16384 + (y * 4 + py) * 128 + x * 4 + pxs];
    }
  }
}

// ---------------------------------------------------------------------------
extern "C" void kernel_launch(void* const* d_in, const int* in_sizes, int n_in,
                              void* d_out, int out_size, void* d_ws, size_t ws_size,
                              hipStream_t stream) {
  const float* frames0 = (const float*)d_in[0];
  const float* st_cx = (const float*)d_in[2];
  const float* st_ch = (const float*)d_in[3];
  const float* st_cm = (const float*)d_in[4];
  const float* st_co = (const float*)d_in[5];
  const float* st_cl = (const float*)d_in[6];
  const float* mb_t = (const float*)d_in[7];
  const float* mb_s = (const float*)d_in[8];
  const float* mb_x = (const float*)d_in[9];
  const float* mb_mh = (const float*)d_in[10];
  const float* mb_mx = (const float*)d_in[11];
  const float* mb_ctw = (const float*)d_in[12];
  const float* mb_ocw = (const float*)d_in[13];
  const float* mb_last = (const float*)d_in[14];
  const float* mn_ch = (const float*)d_in[15];
  const float* mn_cx = (const float*)d_in[16];
  const float* mn_ctw = (const float*)d_in[17];
  const float* mn_ocw = (const float*)d_in[18];
  const float* w_last = (const float*)d_in[19];
  float* out = (float*)d_out;

  float* ws = (float*)d_ws;
  size_t off = 0;
  auto A_ = [&](size_t n) { float* p = ws + off; off += n; return p; };
  float* hs[4]; for (int i = 0; i < 4; ++i) hs[i] = A_(S);
  float* cs[4]; for (int i = 0; i < 4; ++i) cs[i] = A_(S);
  float* membBuf[2]; for (int i = 0; i < 2; ++i) membBuf[i] = A_(S);
  float* dhBuf[3][2];
  for (int i = 0; i < 3; ++i) { dhBuf[i][0] = A_(S); dhBuf[i][1] = A_(S); }
  float* dcb[3]; for (int i = 0; i < 3; ++i) dcb[i] = A_(S);
  float* ccb[3]; for (int i = 0; i < 3; ++i) ccb[i] = A_(S);
  float* diffb = A_(S);
  size_t zeroFloats = off;
  float* xgen = A_(131072);
  float* netb = A_(131072);
  float* R2 = A_(3 * S);  // T
  float* R3 = A_(4 * S);  // X
  float* R5 = A_(4 * S);  // Sconv
  float* RM = A_(4 * S);  // MH
  float* oStB = A_(S);
  float* wtwl = A_(1024);
  us* warena = (us*)(ws + off);

  size_t wOff = 0;
  auto alloc = [&](int taps, int KS) {
    size_t o = wOff;
    wOff += (size_t)2 * taps * KS * 2048;
    return o;
  };
  size_t oSTH0n = alloc(25, 1), oSTH0h = alloc(25, 4);
  size_t oSTH1n = alloc(25, 1), oSTH1h = alloc(25, 4);
  size_t oSTM0n = alloc(25, 1), oSTM0m = alloc(25, 4);
  size_t oSTM1n = alloc(25, 1), oSTM1m = alloc(25, 4);
  size_t oSTOa = alloc(25, 4), oSTOb = alloc(25, 4);
  size_t oCLa = alloc(1, 4), oCLb = alloc(1, 4);
  size_t oMNa0[3], oMNa1[3], oMNb0[3], oMNb1[3], oS0[3], oS1[3], oT0[3], oT1[3],
      oX0[3], oX1[3], oMH0[3], oMH1[3], oMX0[3], oMX1[3], oMBa[3], oMBb[3];
  for (int li = 0; li < 3; ++li) {
    oMNa0[li] = alloc(25, 4); oMNa1[li] = alloc(25, 4);
    oMNb0[li] = alloc(25, 4); oMNb1[li] = alloc(25, 4);
    oS0[li] = alloc(25, 4); oS1[li] = alloc(25, 4);
    oT0[li] = alloc(25, 4); oT1[li] = alloc(25, 4);
    oX0[li] = alloc(25, 4); oX1[li] = alloc(25, 4);
    oMH0[li] = alloc(25, 4); oMH1[li] = alloc(25, 4);
    oMX0[li] = alloc(25, 4); oMX1[li] = alloc(25, 4);
    oMBa[li] = alloc(1, 4); oMBb[li] = alloc(1, 4);
  }
  if (ws_size < off * sizeof(float) + wOff * sizeof(us)) return;

  hipMemsetAsync(ws, 0, zeroFloats * sizeof(float), stream);
  hipMemsetAsync(warena, 0, wOff * sizeof(us), stream);

  auto packL = [&](size_t dstOff, const float* src, int srcRow0, int nRows,
                   int dstRow0, int ciBase, int cinSrc, int taps, int KS) {
    int total = taps * KS * 4 * 64;
    pack_k<<<(total + 255) / 256, 256, 0, stream>>>(warena + dstOff, src, srcRow0,
                                                    nRows, dstRow0, ciBase, cinSrc,
                                                    taps, KS);
  };
  packL(oSTH0n, st_cx, 0, 128, 0, 0, 16, 25, 1);
  packL(oSTH0h, st_ch, 0, 128, 0, 0, 64, 25, 4);
  packL(oSTH1n, st_cx, 128, 64, 0, 0, 16, 25, 1);
  packL(oSTH1n, st_cx, 384, 64, 64, 0, 16, 25, 1);
  packL(oSTH1h, st_ch, 128, 128, 0, 0, 64, 25, 4);
  packL(oSTM0n, st_cx, 192, 128, 0, 0, 16, 25, 1);
  packL(oSTM0m, st_cm, 0, 128, 0, 0, 64, 25, 4);
  packL(oSTM1n, st_cx, 320, 64, 0, 0, 16, 25, 1);
  packL(oSTM1m, st_cm, 128, 64, 0, 0, 64, 25, 4);
  packL(oSTOa, st_co, 0, 64, 0, 0, 128, 25, 4);
  packL(oSTOb, st_co, 0, 64, 0, 64, 128, 25, 4);
  packL(oCLa, st_cl, 0, 64, 0, 0, 128, 1, 4);
  packL(oCLb, st_cl, 0, 64, 0, 64, 128, 1, 4);
  for (int li = 0; li < 3; ++li) {
    const float* ch = mn_ch + (size_t)li * 409600;
    const float* cx = mn_cx + (size_t)li * 409600;
    const float* mbs = mb_s + (size_t)li * 409600;
    const float* mbt = mb_t + (size_t)li * 307200;
    const float* mbx = mb_x + (size_t)li * 409600;
    const float* mmh = mb_mh + (size_t)li * 409600;
    const float* mmx = mb_mx + (size_t)li * 409600;
    const float* mbl = mb_last + (size_t)li * 8192;
    packL(oMNa0[li], ch, 0, 128, 0, 0, 64, 25, 4);
    packL(oMNa1[li], ch, 128, 128, 0, 0, 64, 25, 4);
    packL(oMNb0[li], cx, 0, 128, 0, 0, 64, 25, 4);
    packL(oMNb1[li], cx, 128, 128, 0, 0, 64, 25, 4);
    packL(oS0[li], mbs, 0, 128, 0, 0, 64, 25, 4);
    packL(oS1[li], mbs, 128, 128, 0, 0, 64, 25, 4);
    packL(oT0[li], mbt, 0, 128, 0, 0, 64, 25, 4);
    packL(oT1[li], mbt, 128, 64, 0, 0, 64, 25, 4);
    packL(oX0[li], mbx, 0, 128, 0, 0, 64, 25, 4);
    packL(oX1[li], mbx, 128, 128, 0, 0, 64, 25, 4);
    packL(oMH0[li], mmh, 0, 128, 0, 0, 64, 25, 4);
    packL(oMH1[li], mmh, 128, 128, 0, 0, 64, 25, 4);
    packL(oMX0[li], mmx, 0, 128, 0, 0, 64, 25, 4);
    packL(oMX1[li], mmx, 128, 128, 0, 0, 64, 25, 4);
    packL(oMBa[li], mbl, 0, 64, 0, 0, 128, 1, 4);
    packL(oMBb[li], mbl, 0, 64, 0, 64, 128, 1, 4);
  }
  tr1_k<<<4, 256, 0, stream>>>(w_last, wtwl, 64, 16);
  build_net_k<<<512, 256, 0, stream>>>(frames0, netb, 0);

  auto mkp = [&](const float* x0, size_t w0, int cin0, const float* x1, size_t w1,
                 int cin1, float* o, int outCo, int coBase, int coCnt) {
    Job j;
    j.x0 = x0; j.w0a = warena + w0; j.w0b = warena + w0; j.cin0 = cin0;
    j.x1 = x1; j.w1a = warena + w1; j.w1b = warena + w1; j.cin1 = cin1;
    j.taps = 25; j.type = 0;
    j.out = o; j.outCo = outCo; j.coBase = coBase; j.coCnt = coCnt; j.blockStart = 0;
    return j;
  };
  auto launchB = [&](Batch& bt) {
    int nb = 0;
    for (int q = 0; q < bt.n; ++q) {
      bt.j[q].blockStart = nb;
      nb += (bt.j[q].type == 0) ? 64 : 128;
    }
    convB_k<<<nb, 256, 0, stream>>>(bt);
  };

  for (int t = 0; t < 19; ++t) {
    const float* stIn = (t < 10) ? netb : xgen;
    float* mIn = membBuf[t & 1];
    float* mOut = membBuf[(t + 1) & 1];
    sthstm_k<<<128, 256, 0, stream>>>(
        stIn, hs[0], mIn, warena + oSTH0n, warena + oSTH1n, warena + oSTH0h,
        warena + oSTH1h, warena + oSTM0n, warena + oSTM1n, warena + oSTM0m,
        warena + oSTM1m, cs[0], mOut, oStB);
    stocl_k<<<64, 256, 0, stream>>>(cs[0], mOut, warena + oSTOa, warena + oSTOb,
                                    warena + oCLa, warena + oCLb, oStB, hs[0], diffb);
    for (int i = 1; i < 4; ++i) {
      int li = i - 1;
      float* dhIn = dhBuf[li][t & 1];
      float* dhOut = dhBuf[li][(t + 1) & 1];
      const float* din = (i == 1) ? diffb : dhBuf[li - 1][(t + 1) & 1];
      {  // launch A
        Batch P; int n = 0;
        if (t >= 1) {
          Job j = mkp(dhIn, oMNa0[li], 64, din, oMNb0[li], 64, nullptr, 0, 0, 256);
          j.type = 2;
          j.w0a = warena + oMNa0[li]; j.w0b = warena + oMNa1[li];
          j.w1a = warena + oMNb0[li]; j.w1b = warena + oMNb1[li];
          P.j[n++] = j;
        }
        P.j[n++] = mkp(mOut, oS0[li], 64, nullptr, oS0[li], 0, R5, 256, 0, 128);
        P.j[n++] = mkp(mOut, oS1[li], 64, nullptr, oS1[li], 0, R5, 256, 128, 128);
        P.j[n++] = mkp(hs[i - 1], oX0[li], 64, nullptr, oX0[li], 0, R3, 256, 0, 128);
        P.j[n++] = mkp(hs[i - 1], oX1[li], 64, nullptr, oX1[li], 0, R3, 256, 128, 128);
        P.j[n++] = mkp(hs[i], oT0[li], 64, nullptr, oT0[li], 0, R2, 192, 0, 128);
        P.j[n++] = mkp(hs[i], oT1[li], 64, nullptr, oT1[li], 0, R2, 192, 128, 64);
        P.j[n++] = mkp(cs[i], oMH0[li], 64, nullptr, oMH0[li], 0, RM, 256, 0, 128);
        P.j[n++] = mkp(cs[i], oMH1[li], 64, nullptr, oMH1[li], 0, RM, 256, 128, 128);
        P.n = n;
        P.ctx.gmode = 1;
        P.ctx.ctw = mn_ctw + (size_t)li * 131072;
        P.ctx.ocw = mn_ocw + (size_t)li * 65536;
        P.ctx.dc = dcb[li]; P.ctx.dhOut = dhOut;
        P.ctx.Sb = P.ctx.Tb = P.ctx.Xb = P.ctx.QH = nullptr;
        P.ctx.mPtr = P.ctx.cPtr = P.ctx.ccPtr = nullptr;
        launchB(P);
      }
      {  // launch B: MX fused + mb_gate1
        Batch Q;
        Job j = mkp(dhOut, oMX0[li], 64, nullptr, oMX0[li], 0, nullptr, 0, 0, 256);
        j.type = 2;
        j.w0a = warena + oMX0[li]; j.w0b = warena + oMX1[li];
        j.cin1 = 0;
        Q.j[0] = j; Q.n = 1;
        Q.ctx.gmode = 2;
        Q.ctx.ctw = mb_ctw + (size_t)li * 131072;
        Q.ctx.ocw = mb_ocw + (size_t)li * 65536;
        Q.ctx.dc = nullptr; Q.ctx.dhOut = nullptr;
        Q.ctx.Sb = R5; Q.ctx.Tb = R2; Q.ctx.Xb = R3; Q.ctx.QH = RM;
        Q.ctx.mPtr = mOut; Q.ctx.cPtr = cs[i]; Q.ctx.ccPtr = ccb[li];
        launchB(Q);
      }
      mbl_k<<<64, 256, 0, stream>>>(cs[i], mOut, warena + oMBa[li], warena + oMBb[li],
                                    R5, R2, R3, hs[i], (i == 3) ? 1 : 0, wtwl, xgen,
                                    out, netb, frames0, t);
    }
  }
}